// Round 2
// baseline (762.831 us; speedup 1.0000x reference)
//
#include <hip/hip_runtime.h>
#include <stdint.h>

// CausalSelfAttention  B=2 L=4096 D=768 H=12 Dh=64
// Inputs may be fp32 (reference dtype) or bf16 (harness-lowered); detected
// on-device. Internals are bf16 MFMA everywhere.
// ws layout: [0..64) int flag (1=fp32 inputs); then bf16 planes:
//   qkv q/k/v planes [B*H][L][64], then y [B*L][768].
#define BB 2
#define LL 4096
#define DD 768
#define HH 12
#define DH 64
#define MM (BB * LL)
#define NQKV (3 * DD)
#define PLANE ((size_t)BB * HH * LL * DH)

typedef __attribute__((ext_vector_type(8))) short bf16x8;
typedef __attribute__((ext_vector_type(4))) float f32x4;

__device__ __forceinline__ float bf2f(uint16_t u) {
  union { uint32_t u; float f; } c; c.u = ((uint32_t)u) << 16; return c.f;
}
__device__ __forceinline__ uint16_t f2bf(float f) {
  union { float f; uint32_t u; } c; c.f = f;
  return (uint16_t)((c.u + 0x7FFFu + ((c.u >> 16) & 1u)) >> 16);
}

union H8 { uint16_t h[8]; uint4 v; };

// load 8 consecutive elements at flat index idx, as bf16
template <bool F32>
__device__ __forceinline__ H8 load8(const void* p, size_t idx) {
  H8 r;
  if (F32) {
    const float* f = (const float*)p + idx;
    float4 a = *(const float4*)f;
    float4 b = *(const float4*)(f + 4);
    r.h[0] = f2bf(a.x); r.h[1] = f2bf(a.y); r.h[2] = f2bf(a.z); r.h[3] = f2bf(a.w);
    r.h[4] = f2bf(b.x); r.h[5] = f2bf(b.y); r.h[6] = f2bf(b.z); r.h[7] = f2bf(b.w);
  } else {
    r.v = *(const uint4*)((const uint16_t*)p + idx);
  }
  return r;
}

template <bool F32>
__device__ __forceinline__ float ldscalar(const void* p, int i) {
  return F32 ? ((const float*)p)[i] : bf2f(((const uint16_t*)p)[i]);
}

// ---------------- dtype detection ------------------------------------------
__global__ void detect_k(const uint16_t* __restrict__ x, int* __restrict__ flag) {
  __shared__ int cnt;
  if (threadIdx.x == 0) cnt = 0;
  __syncthreads();
  int c = 0;
  for (int i = threadIdx.x; i < 4096; i += 256) {
    int e = (x[i] >> 7) & 0xFF;          // bf16 exponent field
    if (e == 0xFF || e > 133 || e < 100) c++;   // |v|>64, |v|<2^-27, nan/inf
  }
  atomicAdd(&cnt, c);
  __syncthreads();
  if (threadIdx.x == 0) *flag = (cnt > 512) ? 1 : 0;
}

// ---------------- 64x64-tile GEMM core (K=768), 4 waves, BK=32 -------------
template <bool F32>
__device__ __forceinline__ void gemm64x64(const void* __restrict__ X,
                                          const void* __restrict__ W,
                                          int N, int m0, int n0, f32x4 acc[4]) {
  __shared__ uint16_t As[64][32];   // [m][k]
  __shared__ uint16_t Bs[64][32];   // [n][k] (transposed)
  const int K = 768;
  const int tid = threadIdx.x;
  const int lane = tid & 63, wv = tid >> 6;
  const int quad = lane >> 4, c16 = lane & 15;
  const int arow = tid >> 2, acol = (tid & 3) << 3;  // 64 rows x 4 chunks of 8
  const int brow = tid >> 3, bcol = (tid & 7) << 3;  // 32 k-rows x 8 chunks of 8
  for (int k0 = 0; k0 < K; k0 += 32) {
    H8 av = load8<F32>(X, (size_t)(m0 + arow) * K + k0 + acol);
    H8 bv = load8<F32>(W, (size_t)(k0 + brow) * N + n0 + bcol);
    *(uint4*)(&As[arow][acol]) = av.v;
#pragma unroll
    for (int j = 0; j < 8; ++j) Bs[bcol + j][brow] = bv.h[j];
    __syncthreads();
    bf16x8 a = *(const bf16x8*)(&As[wv * 16 + c16][quad * 8]);
#pragma unroll
    for (int f = 0; f < 4; ++f) {
      bf16x8 b = *(const bf16x8*)(&Bs[f * 16 + c16][quad * 8]);
      acc[f] = __builtin_amdgcn_mfma_f32_16x16x32_bf16(a, b, acc[f], 0, 0, 0);
    }
    __syncthreads();
  }
}

// ---------------- kernel 1: QKV projection ---------------------------------
template <bool F32>
__device__ __forceinline__ void qkv_body(const void* X, const void* W,
                                         const void* bias, uint16_t* qkv) {
  const int m0 = blockIdx.x * 64, n0 = blockIdx.y * 64;
  f32x4 acc[4] = {{0.f,0.f,0.f,0.f},{0.f,0.f,0.f,0.f},{0.f,0.f,0.f,0.f},{0.f,0.f,0.f,0.f}};
  gemm64x64<F32>(X, W, NQKV, m0, n0, acc);
  const int lane = threadIdx.x & 63, wv = threadIdx.x >> 6;
  const int quad = lane >> 4, c16 = lane & 15;
#pragma unroll
  for (int f = 0; f < 4; ++f) {
    int n = n0 + f * 16 + c16;
    int which = n / DD;              // 0=q 1=k 2=v (block-uniform)
    int rem = n - which * DD;
    int hh = rem >> 6, dd = rem & 63;
    uint16_t* dst = qkv + (size_t)which * PLANE;
    float bv = ldscalar<F32>(bias, n);
#pragma unroll
    for (int r = 0; r < 4; ++r) {
      int m = m0 + wv * 16 + quad * 4 + r;   // m = b*L + l
      int b = m >> 12, l = m & (LL - 1);
      dst[((size_t)(b * HH + hh) * LL + l) * DH + dd] = f2bf(acc[f][r] + bv);
    }
  }
}
__global__ __launch_bounds__(256) void qkv_gemm_k(const void* X, const void* W,
                                                  const void* bias, uint16_t* qkv,
                                                  const int* flag) {
  if (*flag) qkv_body<true>(X, W, bias, qkv);
  else       qkv_body<false>(X, W, bias, qkv);
}

// ---------------- kernel 2: flash attention (causal) -----------------------
__global__ __launch_bounds__(256) void attn_k(const uint16_t* __restrict__ qkv,
                                              uint16_t* __restrict__ y) {
  __shared__ uint16_t Ks[64][64];      // [key][d]
  __shared__ uint16_t Vt[64][64];      // [d][key]
  __shared__ uint16_t Ps[4][16][64];   // per-wave [q][key]
  const int qi = blockIdx.x;
  const int bh = blockIdx.y;
  const uint16_t* qb = qkv + (size_t)bh * LL * DH;
  const uint16_t* kb = qb + PLANE;
  const uint16_t* vb = qb + 2 * PLANE;
  const int tid = threadIdx.x, lane = tid & 63, wv = tid >> 6;
  const int quad = lane >> 4, c16 = lane & 15;
  const int q0 = qi * 64;

  const size_t qoff = (size_t)(q0 + wv * 16 + c16) * DH;
  bf16x8 qf0 = *(const bf16x8*)(qb + qoff + quad * 8);
  bf16x8 qf1 = *(const bf16x8*)(qb + qoff + 32 + quad * 8);

  f32x4 o[4] = {{0.f,0.f,0.f,0.f},{0.f,0.f,0.f,0.f},{0.f,0.f,0.f,0.f},{0.f,0.f,0.f,0.f}};
  float m_i[4] = {-1e30f, -1e30f, -1e30f, -1e30f};
  float l_i[4] = {0.f, 0.f, 0.f, 0.f};

  const int ntiles = qi + 1;
  for (int t = 0; t < ntiles; ++t) {
    __syncthreads();   // prior iteration's LDS reads complete
#pragma unroll
    for (int c = 0; c < 2; ++c) {
      int idx = tid + c * 256;
      int row = idx >> 3, c8 = (idx & 7) << 3;
      *(uint4*)(&Ks[row][c8]) = *(const uint4*)(kb + (size_t)(t * 64 + row) * DH + c8);
      uint4 vv = *(const uint4*)(vb + (size_t)(t * 64 + row) * DH + c8);
      const uint16_t* pv = (const uint16_t*)&vv;
#pragma unroll
      for (int j = 0; j < 8; ++j) Vt[c8 + j][row] = pv[j];
    }
    __syncthreads();

    f32x4 s[4];
#pragma unroll
    for (int f = 0; f < 4; ++f) {
      bf16x8 k0 = *(const bf16x8*)(&Ks[f * 16 + c16][quad * 8]);
      bf16x8 k1 = *(const bf16x8*)(&Ks[f * 16 + c16][32 + quad * 8]);
      f32x4 z = {0.f, 0.f, 0.f, 0.f};
      z = __builtin_amdgcn_mfma_f32_16x16x32_bf16(qf0, k0, z, 0, 0, 0);
      z = __builtin_amdgcn_mfma_f32_16x16x32_bf16(qf1, k1, z, 0, 0, 0);
      s[f] = z;
    }
    const int qrow0 = q0 + wv * 16 + quad * 4;
    float rowmax[4] = {-1e30f, -1e30f, -1e30f, -1e30f};
#pragma unroll
    for (int f = 0; f < 4; ++f) {
      int key = t * 64 + f * 16 + c16;
#pragma unroll
      for (int r = 0; r < 4; ++r) {
        float sv = s[f][r] * 0.125f;
        sv = (key <= qrow0 + r) ? sv : -1e30f;
        s[f][r] = sv;
        rowmax[r] = fmaxf(rowmax[r], sv);
      }
    }
#pragma unroll
    for (int off = 1; off < 16; off <<= 1)
#pragma unroll
      for (int r = 0; r < 4; ++r)
        rowmax[r] = fmaxf(rowmax[r], __shfl_xor(rowmax[r], off));
    float alpha[4];
#pragma unroll
    for (int r = 0; r < 4; ++r) {
      float mn = fmaxf(m_i[r], rowmax[r]);
      alpha[r] = __expf(m_i[r] - mn);
      m_i[r] = mn;
    }
    float rowsum[4] = {0.f, 0.f, 0.f, 0.f};
#pragma unroll
    for (int f = 0; f < 4; ++f)
#pragma unroll
      for (int r = 0; r < 4; ++r) {
        float p = __expf(s[f][r] - m_i[r]);
        s[f][r] = p;
        rowsum[r] += p;
      }
#pragma unroll
    for (int off = 1; off < 16; off <<= 1)
#pragma unroll
      for (int r = 0; r < 4; ++r)
        rowsum[r] += __shfl_xor(rowsum[r], off);
#pragma unroll
    for (int r = 0; r < 4; ++r) l_i[r] = alpha[r] * l_i[r] + rowsum[r];
#pragma unroll
    for (int g = 0; g < 4; ++g)
#pragma unroll
      for (int r = 0; r < 4; ++r) o[g][r] *= alpha[r];

    // P: C layout -> LDS -> A layout
#pragma unroll
    for (int f = 0; f < 4; ++f)
#pragma unroll
      for (int r = 0; r < 4; ++r)
        Ps[wv][quad * 4 + r][f * 16 + c16] = f2bf(s[f][r]);
    __syncthreads();
    bf16x8 pf0 = *(const bf16x8*)(&Ps[wv][c16][quad * 8]);
    bf16x8 pf1 = *(const bf16x8*)(&Ps[wv][c16][32 + quad * 8]);
#pragma unroll
    for (int g = 0; g < 4; ++g) {
      bf16x8 v0 = *(const bf16x8*)(&Vt[g * 16 + c16][quad * 8]);
      bf16x8 v1 = *(const bf16x8*)(&Vt[g * 16 + c16][32 + quad * 8]);
      o[g] = __builtin_amdgcn_mfma_f32_16x16x32_bf16(pf0, v0, o[g], 0, 0, 0);
      o[g] = __builtin_amdgcn_mfma_f32_16x16x32_bf16(pf1, v1, o[g], 0, 0, 0);
    }
  }

  const int b = bh / HH, hh = bh - b * HH;
  float inv[4];
#pragma unroll
  for (int r = 0; r < 4; ++r) inv[r] = 1.f / l_i[r];
#pragma unroll
  for (int g = 0; g < 4; ++g)
#pragma unroll
    for (int r = 0; r < 4; ++r) {
      int l = q0 + wv * 16 + quad * 4 + r;
      y[((size_t)(b * LL + l)) * DD + hh * DH + g * 16 + c16] = f2bf(o[g][r] * inv[r]);
    }
}

// ---------------- kernel 3: output projection ------------------------------
template <bool F32>
__device__ __forceinline__ void out_body(const uint16_t* Y, const void* W,
                                         const void* bias, void* out) {
  const int m0 = blockIdx.x * 64, n0 = blockIdx.y * 64;
  f32x4 acc[4] = {{0.f,0.f,0.f,0.f},{0.f,0.f,0.f,0.f},{0.f,0.f,0.f,0.f},{0.f,0.f,0.f,0.f}};
  gemm64x64<F32>(Y, W, DD, m0, n0, acc);  // Y staged via load8<F32>? no: Y is bf16
  // NOTE: gemm64x64<F32> applies F32 to BOTH operands; Y is always bf16, so
  // out_body is only instantiated via out_gemm_k below which handles this.
}

// Y (bf16 always) x Wo (dual dtype): specialized GEMM
template <bool F32>
__device__ __forceinline__ void out_gemm_body(const uint16_t* __restrict__ Yb,
                                              const void* __restrict__ W,
                                              const void* __restrict__ bias,
                                              void* __restrict__ out) {
  __shared__ uint16_t As[64][32];
  __shared__ uint16_t Bs[64][32];
  const int K = 768, N = DD;
  const int m0 = blockIdx.x * 64, n0 = blockIdx.y * 64;
  const int tid = threadIdx.x;
  const int lane = tid & 63, wv = tid >> 6;
  const int quad = lane >> 4, c16 = lane & 15;
  const int arow = tid >> 2, acol = (tid & 3) << 3;
  const int brow = tid >> 3, bcol = (tid & 7) << 3;
  f32x4 acc[4] = {{0.f,0.f,0.f,0.f},{0.f,0.f,0.f,0.f},{0.f,0.f,0.f,0.f},{0.f,0.f,0.f,0.f}};
  for (int k0 = 0; k0 < K; k0 += 32) {
    H8 av = load8<false>(Yb, (size_t)(m0 + arow) * K + k0 + acol);
    H8 bv = load8<F32>(W, (size_t)(k0 + brow) * N + n0 + bcol);
    *(uint4*)(&As[arow][acol]) = av.v;
#pragma unroll
    for (int j = 0; j < 8; ++j) Bs[bcol + j][brow] = bv.h[j];
    __syncthreads();
    bf16x8 a = *(const bf16x8*)(&As[wv * 16 + c16][quad * 8]);
#pragma unroll
    for (int f = 0; f < 4; ++f) {
      bf16x8 b = *(const bf16x8*)(&Bs[f * 16 + c16][quad * 8]);
      acc[f] = __builtin_amdgcn_mfma_f32_16x16x32_bf16(a, b, acc[f], 0, 0, 0);
    }
    __syncthreads();
  }
#pragma unroll
  for (int f = 0; f < 4; ++f) {
    int n = n0 + f * 16 + c16;
    float bv = ldscalar<F32>(bias, n);
#pragma unroll
    for (int r = 0; r < 4; ++r) {
      int m = m0 + wv * 16 + quad * 4 + r;
      float val = acc[f][r] + bv;
      if (F32) ((float*)out)[(size_t)m * DD + n] = val;
      else     ((uint16_t*)out)[(size_t)m * DD + n] = f2bf(val);
    }
  }
}
__global__ __launch_bounds__(256) void out_gemm_k(const uint16_t* Yb, const void* W,
                                                  const void* bias, void* out,
                                                  const int* flag) {
  if (*flag) out_gemm_body<true>(Yb, W, bias, out);
  else       out_gemm_body<false>(Yb, W, bias, out);
}

extern "C" void kernel_launch(void* const* d_in, const int* in_sizes, int n_in,
                              void* d_out, int out_size, void* d_ws, size_t ws_size,
                              hipStream_t stream) {
  const void* x    = d_in[0];
  const void* Wqkv = d_in[1];
  const void* bqkv = d_in[2];
  const void* Wo   = d_in[3];
  const void* bo   = d_in[4];
  int* flagp = (int*)d_ws;
  uint16_t* qkv_ws = (uint16_t*)((char*)d_ws + 64);
  uint16_t* y_ws   = qkv_ws + 3 * PLANE;

  detect_k<<<1, 256, 0, stream>>>((const uint16_t*)x, flagp);
  qkv_gemm_k<<<dim3(MM / 64, NQKV / 64), 256, 0, stream>>>(x, Wqkv, bqkv, qkv_ws, flagp);
  attn_k<<<dim3(LL / 64, BB * HH), 256, 0, stream>>>(qkv_ws, y_ws);
  out_gemm_k<<<dim3(MM / 64, DD / 64), 256, 0, stream>>>(y_ws, Wo, bo, d_out, flagp);
}

// Round 3
// 390.893 us; speedup vs baseline: 1.9515x; 1.9515x over previous
//
#include <hip/hip_runtime.h>
#include <stdint.h>

// CausalSelfAttention  B=2 L=4096 D=768 H=12 Dh=64
// Dual-dtype inputs (fp32 reference or bf16-lowered), detected on device.
// Internals bf16 MFMA. ws: flag(64B) | q,k planes [bh][l][64] | vT plane
// [bh][d][L] | y/xbf overlay [8192][768] | WqkvT [2304][768] | WoT [768][768]
#define BB 2
#define LL 4096
#define DD 768
#define HH 12
#define DH 64
#define MM (BB * LL)
#define NQKV (3 * DD)
#define KK 768
#define PLANE ((size_t)BB * HH * LL * DH)
#define SQSCALE 0.1803368801111204f   // 0.125 * log2(e)

typedef __attribute__((ext_vector_type(8))) short bf16x8;
typedef __attribute__((ext_vector_type(4))) float f32x4;

__device__ __forceinline__ float bf2f(uint16_t u) {
  union { uint32_t u; float f; } c; c.u = ((uint32_t)u) << 16; return c.f;
}
__device__ __forceinline__ uint16_t f2bf(float f) {
  union { float f; uint32_t u; } c; c.f = f;
  return (uint16_t)((c.u + 0x7FFFu + ((c.u >> 16) & 1u)) >> 16);
}

union H8 { uint16_t h[8]; uint4 v; };

template <bool F32>
__device__ __forceinline__ H8 load8(const void* p, size_t idx) {
  H8 r;
  if (F32) {
    const float* f = (const float*)p + idx;
    float4 a = *(const float4*)f;
    float4 b = *(const float4*)(f + 4);
    r.h[0] = f2bf(a.x); r.h[1] = f2bf(a.y); r.h[2] = f2bf(a.z); r.h[3] = f2bf(a.w);
    r.h[4] = f2bf(b.x); r.h[5] = f2bf(b.y); r.h[6] = f2bf(b.z); r.h[7] = f2bf(b.w);
  } else {
    r.v = *(const uint4*)((const uint16_t*)p + idx);
  }
  return r;
}

// async global->LDS, 16B per lane; lds ptr must be wave-uniform
__device__ __forceinline__ void g2l16(const uint16_t* g, uint16_t* l) {
  __builtin_amdgcn_global_load_lds((const __attribute__((address_space(1))) void*)g,
                                   (__attribute__((address_space(3))) void*)l,
                                   16, 0, 0);
}

// ---------------- dtype detection ------------------------------------------
__global__ void detect_k(const uint16_t* __restrict__ x, int* __restrict__ flag) {
  __shared__ int cnt;
  if (threadIdx.x == 0) cnt = 0;
  __syncthreads();
  int c = 0;
  for (int i = threadIdx.x; i < 4096; i += 256) {
    int e = (x[i] >> 7) & 0xFF;
    if (e == 0xFF || e > 133 || e < 100) c++;
  }
  atomicAdd(&cnt, c);
  __syncthreads();
  if (threadIdx.x == 0) *flag = (cnt > 512) ? 1 : 0;
}

// ---------------- x -> bf16 ------------------------------------------------
__global__ __launch_bounds__(256) void convert_x_k(const void* __restrict__ x,
                                                   uint16_t* __restrict__ xbf,
                                                   const int* __restrict__ flag) {
  const int fl = *flag;
  const size_t nchunks = (size_t)MM * DD / 8;
  for (size_t i = blockIdx.x * 256 + threadIdx.x; i < nchunks; i += (size_t)gridDim.x * 256) {
    H8 v = fl ? load8<true>(x, i * 8) : load8<false>(x, i * 8);
    *(uint4*)(xbf + i * 8) = v.v;
  }
}

// ---------------- W[k][n] -> WT[n][k] (+convert) ---------------------------
__global__ __launch_bounds__(256) void wt_k(const void* __restrict__ W,
                                            uint16_t* __restrict__ WT,
                                            int N, const int* __restrict__ flag) {
  __shared__ uint16_t Ts[64][65];
  const int fl = *flag;
  const int n0 = blockIdx.x * 64, k0 = blockIdx.y * 64;
  const int tid = threadIdx.x;
#pragma unroll
  for (int j = 0; j < 16; ++j) {
    int idx = tid + j * 256;
    int r = idx >> 6, c = idx & 63;
    size_t gi = (size_t)(k0 + r) * N + n0 + c;
    float v = fl ? ((const float*)W)[gi] : bf2f(((const uint16_t*)W)[gi]);
    Ts[c][r] = f2bf(v);
  }
  __syncthreads();
#pragma unroll
  for (int j = 0; j < 16; ++j) {
    int idx = tid + j * 256;
    int n = idx >> 6, k = idx & 63;
    WT[(size_t)(n0 + n) * KK + k0 + k] = Ts[n][k];
  }
}

// ---------------- 128x128 GEMM core (K=768, BK=32, global_load_lds) --------
// As/Bs: [128][32] halves, chunk-swizzled with g(row) = (row>>1)&3.
__device__ __forceinline__ void gemm128_core(const uint16_t* __restrict__ A,
                                             const uint16_t* __restrict__ BT,
                                             int m0, int n0,
                                             uint16_t* As, uint16_t* Bs,
                                             f32x4 acc[4][4]) {
  const int tid = threadIdx.x, lane = tid & 63, w = tid >> 6;
  const int quad = lane >> 4, c16 = lane & 15;
  const int wm = w >> 1, wn = w & 1;
  const int srow = lane >> 2, schunk = lane & 3;
  const int rsw = (c16 >> 1) & 3;   // frag-read swizzle
  for (int k0 = 0; k0 < KK; k0 += 32) {
#pragma unroll
    for (int i = 0; i < 2; ++i) {
      int row = w * 32 + i * 16 + srow;
      int gch = schunk ^ ((row >> 1) & 3);
      g2l16(A + (size_t)(m0 + row) * KK + k0 + gch * 8, As + (w * 32 + i * 16) * 32);
      g2l16(BT + (size_t)(n0 + row) * KK + k0 + gch * 8, Bs + (w * 32 + i * 16) * 32);
    }
    __syncthreads();
    bf16x8 a[4], b[4];
#pragma unroll
    for (int i = 0; i < 4; ++i) {
      a[i] = *(const bf16x8*)(As + (wm * 64 + i * 16 + c16) * 32 + ((quad ^ rsw) * 8));
      b[i] = *(const bf16x8*)(Bs + (wn * 64 + i * 16 + c16) * 32 + ((quad ^ rsw) * 8));
    }
#pragma unroll
    for (int i = 0; i < 4; ++i)
#pragma unroll
      for (int f = 0; f < 4; ++f)
        acc[i][f] = __builtin_amdgcn_mfma_f32_16x16x32_bf16(a[i], b[f], acc[i][f], 0, 0, 0);
    __syncthreads();
  }
}

// ---------------- kernel: QKV projection (writes q,k,vT planes) ------------
__global__ __launch_bounds__(256) void qkv128_k(const uint16_t* __restrict__ X,
                                                const uint16_t* __restrict__ WT,
                                                const void* __restrict__ bias,
                                                uint16_t* __restrict__ planes,
                                                const int* __restrict__ flag) {
  __shared__ __align__(16) uint16_t As[128 * 32];
  __shared__ __align__(16) uint16_t Bs[128 * 32];
  __shared__ __align__(16) uint16_t Ts[64][136];
  const int fl = *flag;
  const int m0 = blockIdx.x * 128, n0 = blockIdx.y * 128;
  f32x4 acc[4][4];
#pragma unroll
  for (int i = 0; i < 4; ++i)
#pragma unroll
    for (int f = 0; f < 4; ++f) acc[i][f] = (f32x4){0.f, 0.f, 0.f, 0.f};
  gemm128_core(X, WT, m0, n0, As, Bs, acc);

  const int tid = threadIdx.x, lane = tid & 63, w = tid >> 6;
  const int quad = lane >> 4, c16 = lane & 15;
  const int wm = w >> 1, wn = w & 1;
  const int which = (n0 >= 2 * DD) ? 2 : (n0 >= DD ? 1 : 0);

  if (which < 2) {
    // q/k planes: [bh][l][64]; q scaled by SQSCALE
    uint16_t* dst = planes + (size_t)which * PLANE;
    const float sc = (which == 0) ? SQSCALE : 1.0f;
#pragma unroll
    for (int f = 0; f < 4; ++f) {
      int n = n0 + wn * 64 + f * 16 + c16;
      float bv = fl ? ((const float*)bias)[n] : bf2f(((const uint16_t*)bias)[n]);
      int rem = n - which * DD;
      int hh = rem >> 6, dd = rem & 63;
#pragma unroll
      for (int i = 0; i < 4; ++i)
#pragma unroll
        for (int r = 0; r < 4; ++r) {
          int m = m0 + wm * 64 + i * 16 + quad * 4 + r;
          int b = m >> 12, l = m & (LL - 1);
          dst[((size_t)(b * HH + hh) * LL + l) * DH + dd] = f2bf((acc[i][f][r] + bv) * sc);
        }
    }
  } else {
    // v -> vT plane [bh][d][L] via LDS transpose, two n-halves
    uint16_t* vtp = planes + 2 * PLANE;
    const int l0 = m0 & (LL - 1), bb = m0 >> 12;
    for (int half = 0; half < 2; ++half) {
      __syncthreads();
      if (wn == half) {
#pragma unroll
        for (int f = 0; f < 4; ++f) {
          int n = n0 + half * 64 + f * 16 + c16;
          float bv = fl ? ((const float*)bias)[n] : bf2f(((const uint16_t*)bias)[n]);
#pragma unroll
          for (int i = 0; i < 4; ++i)
#pragma unroll
            for (int r = 0; r < 4; ++r)
              Ts[f * 16 + c16][wm * 64 + i * 16 + quad * 4 + r] = f2bf(acc[i][f][r] + bv);
        }
      }
      __syncthreads();
#pragma unroll
      for (int j = 0; j < 4; ++j) {
        int idx = tid + j * 256;          // 1024 chunks = 64 rows x 16
        int nl = idx >> 4, ch = idx & 15;
        int rem = n0 + half * 64 + nl - 2 * DD;
        int hh = rem >> 6, dd = rem & 63;
        uint4 val = *(const uint4*)(&Ts[nl][ch * 8]);
        *(uint4*)(vtp + ((size_t)(bb * HH + hh) * DH + dd) * LL + l0 + ch * 8) = val;
      }
    }
  }
}

// ---------------- kernel: flash attention (causal, paired q-tiles) ---------
__global__ __launch_bounds__(256) void attn_k(const uint16_t* __restrict__ planes,
                                              uint16_t* __restrict__ y) {
  __shared__ __align__(16) uint16_t Ks[64 * 64];
  __shared__ __align__(16) uint16_t Vt[64 * 64];
  __shared__ __align__(16) uint16_t Ps[4 * 16 * 64];
  const int p = blockIdx.x;            // 0..31 -> q tiles {63-p, p}
  const int bh = blockIdx.y;           // 0..23
  const uint16_t* qb = planes + (size_t)bh * LL * DH;
  const uint16_t* kb = qb + PLANE;
  const uint16_t* vtb = planes + 2 * PLANE + (size_t)bh * DH * LL;  // [d][L]
  const int tid = threadIdx.x, lane = tid & 63, wv = tid >> 6;
  const int quad = lane >> 4, c16 = lane & 15;
  const int r0 = tid >> 3, c0 = tid & 7;
  const int sw0 = r0 & 7;              // (r0+32)&7 == sw0
  const int swf = c16 & 7;
  uint16_t* Psb = Ps + wv * 1024;
  const int b = bh / HH, hh = bh - b * HH;

  for (int pass = 0; pass < 2; ++pass) {
    const int qi = pass ? p : 63 - p;
    const int q0 = qi * 64;
    const size_t qoff = (size_t)(q0 + wv * 16 + c16) * DH;
    bf16x8 qf0 = *(const bf16x8*)(qb + qoff + quad * 8);
    bf16x8 qf1 = *(const bf16x8*)(qb + qoff + 32 + quad * 8);

    f32x4 o[4];
#pragma unroll
    for (int g = 0; g < 4; ++g) o[g] = (f32x4){0.f, 0.f, 0.f, 0.f};
    float m_i[4] = {-1e30f, -1e30f, -1e30f, -1e30f};
    float l_i[4] = {0.f, 0.f, 0.f, 0.f};

    uint4 kr0, kr1, vr0, vr1;
    {
      kr0 = *(const uint4*)(kb + (size_t)r0 * DH + c0 * 8);
      kr1 = *(const uint4*)(kb + (size_t)(r0 + 32) * DH + c0 * 8);
      vr0 = *(const uint4*)(vtb + (size_t)r0 * LL + c0 * 8);
      vr1 = *(const uint4*)(vtb + (size_t)(r0 + 32) * LL + c0 * 8);
    }

    for (int t = 0; t <= qi; ++t) {
      __syncthreads();                 // prior tile's LDS reads complete
      *(uint4*)(Ks + r0 * 64 + (c0 ^ sw0) * 8) = kr0;
      *(uint4*)(Ks + (r0 + 32) * 64 + (c0 ^ sw0) * 8) = kr1;
      *(uint4*)(Vt + r0 * 64 + (c0 ^ sw0) * 8) = vr0;
      *(uint4*)(Vt + (r0 + 32) * 64 + (c0 ^ sw0) * 8) = vr1;
      if (t < qi) {
        int t64 = (t + 1) * 64;
        kr0 = *(const uint4*)(kb + (size_t)(t64 + r0) * DH + c0 * 8);
        kr1 = *(const uint4*)(kb + (size_t)(t64 + r0 + 32) * DH + c0 * 8);
        vr0 = *(const uint4*)(vtb + (size_t)r0 * LL + t64 + c0 * 8);
        vr1 = *(const uint4*)(vtb + (size_t)(r0 + 32) * LL + t64 + c0 * 8);
      }
      __syncthreads();                 // staged tile visible

      // S = Q K^T  (exp2 domain: q pre-scaled by 0.125*log2e)
      f32x4 s[4];
#pragma unroll
      for (int f = 0; f < 4; ++f) {
        const uint16_t* krow = Ks + (f * 16 + c16) * 64;
        bf16x8 k0f = *(const bf16x8*)(krow + ((quad ^ swf) * 8));
        bf16x8 k1f = *(const bf16x8*)(krow + (((quad + 4) ^ swf) * 8));
        f32x4 z = {0.f, 0.f, 0.f, 0.f};
        z = __builtin_amdgcn_mfma_f32_16x16x32_bf16(qf0, k0f, z, 0, 0, 0);
        z = __builtin_amdgcn_mfma_f32_16x16x32_bf16(qf1, k1f, z, 0, 0, 0);
        s[f] = z;
      }
      const int qrow0 = q0 + wv * 16 + quad * 4;
      if (t == qi) {                   // diagonal tile: causal mask
#pragma unroll
        for (int f = 0; f < 4; ++f) {
          int key = t * 64 + f * 16 + c16;
#pragma unroll
          for (int r = 0; r < 4; ++r)
            s[f][r] = (key <= qrow0 + r) ? s[f][r] : -3e38f;
        }
      }
      float rowmax[4] = {-3e38f, -3e38f, -3e38f, -3e38f};
#pragma unroll
      for (int f = 0; f < 4; ++f)
#pragma unroll
        for (int r = 0; r < 4; ++r) rowmax[r] = fmaxf(rowmax[r], s[f][r]);
#pragma unroll
      for (int off = 1; off < 16; off <<= 1)
#pragma unroll
        for (int r = 0; r < 4; ++r)
          rowmax[r] = fmaxf(rowmax[r], __shfl_xor(rowmax[r], off));
      float alpha[4];
#pragma unroll
      for (int r = 0; r < 4; ++r) {
        float mn = fmaxf(m_i[r], rowmax[r]);
        alpha[r] = exp2f(m_i[r] - mn);
        m_i[r] = mn;
      }
      float rowsum[4] = {0.f, 0.f, 0.f, 0.f};
#pragma unroll
      for (int f = 0; f < 4; ++f)
#pragma unroll
        for (int r = 0; r < 4; ++r) {
          float pv = exp2f(s[f][r] - m_i[r]);
          s[f][r] = pv;
          rowsum[r] += pv;
        }
#pragma unroll
      for (int off = 1; off < 16; off <<= 1)
#pragma unroll
        for (int r = 0; r < 4; ++r)
          rowsum[r] += __shfl_xor(rowsum[r], off);
#pragma unroll
      for (int r = 0; r < 4; ++r) l_i[r] = alpha[r] * l_i[r] + rowsum[r];
#pragma unroll
      for (int g = 0; g < 4; ++g)
#pragma unroll
        for (int r = 0; r < 4; ++r) o[g][r] *= alpha[r];

      // P: C-layout -> wave-private LDS (swizzled) -> A-layout
#pragma unroll
      for (int f = 0; f < 4; ++f) {
        int cb = f * 2 + (c16 >> 3);
#pragma unroll
        for (int r = 0; r < 4; ++r) {
          int q = quad * 4 + r;
          Psb[q * 64 + ((cb ^ (q & 7)) * 8) + (c16 & 7)] = f2bf(s[f][r]);
        }
      }
      __asm__ __volatile__("s_waitcnt lgkmcnt(0)" ::: "memory");
      bf16x8 pf0 = *(const bf16x8*)(Psb + c16 * 64 + ((quad ^ swf) * 8));
      bf16x8 pf1 = *(const bf16x8*)(Psb + c16 * 64 + (((quad + 4) ^ swf) * 8));
#pragma unroll
      for (int g = 0; g < 4; ++g) {
        const uint16_t* vrow = Vt + (g * 16 + c16) * 64;
        bf16x8 v0 = *(const bf16x8*)(vrow + ((quad ^ swf) * 8));
        bf16x8 v1 = *(const bf16x8*)(vrow + (((quad + 4) ^ swf) * 8));
        o[g] = __builtin_amdgcn_mfma_f32_16x16x32_bf16(pf0, v0, o[g], 0, 0, 0);
        o[g] = __builtin_amdgcn_mfma_f32_16x16x32_bf16(pf1, v1, o[g], 0, 0, 0);
      }
    }

    float inv[4];
#pragma unroll
    for (int r = 0; r < 4; ++r) inv[r] = 1.f / l_i[r];
#pragma unroll
    for (int g = 0; g < 4; ++g)
#pragma unroll
      for (int r = 0; r < 4; ++r) {
        int l = q0 + wv * 16 + quad * 4 + r;
        y[((size_t)(b * LL + l)) * DD + hh * DH + g * 16 + c16] = f2bf(o[g][r] * inv[r]);
      }
  }
}

// ---------------- kernel: output projection --------------------------------
__global__ __launch_bounds__(256) void out128_k(const uint16_t* __restrict__ Y,
                                                const uint16_t* __restrict__ WT,
                                                const void* __restrict__ bias,
                                                void* __restrict__ out,
                                                const int* __restrict__ flag) {
  __shared__ __align__(16) uint16_t As[128 * 32];
  __shared__ __align__(16) uint16_t Bs[128 * 32];
  const int fl = *flag;
  const int m0 = blockIdx.x * 128, n0 = blockIdx.y * 128;
  f32x4 acc[4][4];
#pragma unroll
  for (int i = 0; i < 4; ++i)
#pragma unroll
    for (int f = 0; f < 4; ++f) acc[i][f] = (f32x4){0.f, 0.f, 0.f, 0.f};
  gemm128_core(Y, WT, m0, n0, As, Bs, acc);
  const int lane = threadIdx.x & 63, w = threadIdx.x >> 6;
  const int quad = lane >> 4, c16 = lane & 15;
  const int wm = w >> 1, wn = w & 1;
#pragma unroll
  for (int f = 0; f < 4; ++f) {
    int n = n0 + wn * 64 + f * 16 + c16;
    float bv = fl ? ((const float*)bias)[n] : bf2f(((const uint16_t*)bias)[n]);
#pragma unroll
    for (int i = 0; i < 4; ++i)
#pragma unroll
      for (int r = 0; r < 4; ++r) {
        int m = m0 + wm * 64 + i * 16 + quad * 4 + r;
        float val = acc[i][f][r] + bv;
        if (fl) ((float*)out)[(size_t)m * DD + n] = val;
        else    ((uint16_t*)out)[(size_t)m * DD + n] = f2bf(val);
      }
  }
}

extern "C" void kernel_launch(void* const* d_in, const int* in_sizes, int n_in,
                              void* d_out, int out_size, void* d_ws, size_t ws_size,
                              hipStream_t stream) {
  const void* x    = d_in[0];
  const void* Wqkv = d_in[1];
  const void* bqkv = d_in[2];
  const void* Wo   = d_in[3];
  const void* bo   = d_in[4];
  int* flagp = (int*)d_ws;
  uint16_t* planes = (uint16_t*)((char*)d_ws + 64);          // q,k,vT
  uint16_t* y_ws   = planes + 3 * PLANE;                     // also xbf overlay
  uint16_t* wqkvT  = y_ws + (size_t)MM * DD;
  uint16_t* woT    = wqkvT + (size_t)NQKV * KK;
  uint16_t* xbf    = y_ws;   // overlay: consumed by qkv gemm before attn writes y

  detect_k<<<1, 256, 0, stream>>>((const uint16_t*)x, flagp);
  convert_x_k<<<1024, 256, 0, stream>>>(x, xbf, flagp);
  wt_k<<<dim3(NQKV / 64, KK / 64), 256, 0, stream>>>(Wqkv, wqkvT, NQKV, flagp);
  wt_k<<<dim3(DD / 64, KK / 64), 256, 0, stream>>>(Wo, woT, DD, flagp);
  qkv128_k<<<dim3(MM / 128, NQKV / 128), 256, 0, stream>>>(xbf, wqkvT, bqkv, planes, flagp);
  attn_k<<<dim3(32, BB * HH), 256, 0, stream>>>(planes, y_ws);
  out128_k<<<dim3(MM / 128, DD / 128), 256, 0, stream>>>(y_ws, woT, bo, d_out, flagp);
}

// Round 4
// 286.275 us; speedup vs baseline: 2.6647x; 1.3654x over previous
//
#include <hip/hip_runtime.h>
#include <stdint.h>

// CausalSelfAttention  B=2 L=4096 D=768 H=12 Dh=64
// Dual-dtype inputs (fp32 reference or bf16-lowered), detected on device.
// Internals bf16 MFMA. ws: flag(64B) | q,k planes [bh][l][64] | vT plane
// [bh][d][L] | y/xbf overlay [8192][768] | WqkvT [2304][768] | WoT [768][768]
#define BB 2
#define LL 4096
#define DD 768
#define HH 12
#define DH 64
#define MM (BB * LL)
#define NQKV (3 * DD)
#define KK 768
#define PLANE ((size_t)BB * HH * LL * DH)
#define SQSCALE 0.1803368801111204f   // 0.125 * log2(e)

typedef __attribute__((ext_vector_type(8))) short bf16x8;
typedef __attribute__((ext_vector_type(4))) float f32x4;

__device__ __forceinline__ float bf2f(uint16_t u) {
  union { uint32_t u; float f; } c; c.u = ((uint32_t)u) << 16; return c.f;
}
__device__ __forceinline__ uint16_t f2bf(float f) {
  union { float f; uint32_t u; } c; c.f = f;
  return (uint16_t)((c.u + 0x7FFFu + ((c.u >> 16) & 1u)) >> 16);
}

union H8 { uint16_t h[8]; uint4 v; };
union B8 { uint2 d[2]; bf16x8 v; };

template <bool F32>
__device__ __forceinline__ H8 load8(const void* p, size_t idx) {
  H8 r;
  if (F32) {
    const float* f = (const float*)p + idx;
    float4 a = *(const float4*)f;
    float4 b = *(const float4*)(f + 4);
    r.h[0] = f2bf(a.x); r.h[1] = f2bf(a.y); r.h[2] = f2bf(a.z); r.h[3] = f2bf(a.w);
    r.h[4] = f2bf(b.x); r.h[5] = f2bf(b.y); r.h[6] = f2bf(b.z); r.h[7] = f2bf(b.w);
  } else {
    r.v = *(const uint4*)((const uint16_t*)p + idx);
  }
  return r;
}

// async global->LDS, 16B per lane; lds ptr must be wave-uniform
__device__ __forceinline__ void g2l16(const uint16_t* g, uint16_t* l) {
  __builtin_amdgcn_global_load_lds((const __attribute__((address_space(1))) void*)g,
                                   (__attribute__((address_space(3))) void*)l,
                                   16, 0, 0);
}

// ---------------- dtype detection ------------------------------------------
__global__ void detect_k(const uint16_t* __restrict__ x, int* __restrict__ flag) {
  __shared__ int cnt;
  if (threadIdx.x == 0) cnt = 0;
  __syncthreads();
  int c = 0;
  for (int i = threadIdx.x; i < 4096; i += 256) {
    int e = (x[i] >> 7) & 0xFF;
    if (e == 0xFF || e > 133 || e < 100) c++;
  }
  atomicAdd(&cnt, c);
  __syncthreads();
  if (threadIdx.x == 0) *flag = (cnt > 512) ? 1 : 0;
}

// ---------------- x -> bf16 ------------------------------------------------
__global__ __launch_bounds__(256) void convert_x_k(const void* __restrict__ x,
                                                   uint16_t* __restrict__ xbf,
                                                   const int* __restrict__ flag) {
  const int fl = *flag;
  const size_t nchunks = (size_t)MM * DD / 8;
  for (size_t i = blockIdx.x * 256 + threadIdx.x; i < nchunks; i += (size_t)gridDim.x * 256) {
    H8 v = fl ? load8<true>(x, i * 8) : load8<false>(x, i * 8);
    *(uint4*)(xbf + i * 8) = v.v;
  }
}

// ---------------- W[k][n] -> WT[n][k] (+convert) ---------------------------
__global__ __launch_bounds__(256) void wt_k(const void* __restrict__ W,
                                            uint16_t* __restrict__ WT,
                                            int N, const int* __restrict__ flag) {
  __shared__ uint16_t Ts[64][65];
  const int fl = *flag;
  const int n0 = blockIdx.x * 64, k0 = blockIdx.y * 64;
  const int tid = threadIdx.x;
#pragma unroll
  for (int j = 0; j < 16; ++j) {
    int idx = tid + j * 256;
    int r = idx >> 6, c = idx & 63;
    size_t gi = (size_t)(k0 + r) * N + n0 + c;
    float v = fl ? ((const float*)W)[gi] : bf2f(((const uint16_t*)W)[gi]);
    Ts[c][r] = f2bf(v);
  }
  __syncthreads();
#pragma unroll
  for (int j = 0; j < 16; ++j) {
    int idx = tid + j * 256;
    int n = idx >> 6, k = idx & 63;
    WT[(size_t)(n0 + n) * KK + k0 + k] = Ts[n][k];
  }
}

// ---------------- 128x128 GEMM core (K=768, BK=32, global_load_lds) --------
__device__ __forceinline__ void gemm128_core(const uint16_t* __restrict__ A,
                                             const uint16_t* __restrict__ BT,
                                             int m0, int n0,
                                             uint16_t* As, uint16_t* Bs,
                                             f32x4 acc[4][4]) {
  const int tid = threadIdx.x, lane = tid & 63, w = tid >> 6;
  const int quad = lane >> 4, c16 = lane & 15;
  const int wm = w >> 1, wn = w & 1;
  const int srow = lane >> 2, schunk = lane & 3;
  const int rsw = (c16 >> 1) & 3;
  for (int k0 = 0; k0 < KK; k0 += 32) {
#pragma unroll
    for (int i = 0; i < 2; ++i) {
      int row = w * 32 + i * 16 + srow;
      int gch = schunk ^ ((row >> 1) & 3);
      g2l16(A + (size_t)(m0 + row) * KK + k0 + gch * 8, As + (w * 32 + i * 16) * 32);
      g2l16(BT + (size_t)(n0 + row) * KK + k0 + gch * 8, Bs + (w * 32 + i * 16) * 32);
    }
    __syncthreads();
    bf16x8 a[4], b[4];
#pragma unroll
    for (int i = 0; i < 4; ++i) {
      a[i] = *(const bf16x8*)(As + (wm * 64 + i * 16 + c16) * 32 + ((quad ^ rsw) * 8));
      b[i] = *(const bf16x8*)(Bs + (wn * 64 + i * 16 + c16) * 32 + ((quad ^ rsw) * 8));
    }
#pragma unroll
    for (int i = 0; i < 4; ++i)
#pragma unroll
      for (int f = 0; f < 4; ++f)
        acc[i][f] = __builtin_amdgcn_mfma_f32_16x16x32_bf16(a[i], b[f], acc[i][f], 0, 0, 0);
    __syncthreads();
  }
}

// ---------------- kernel: QKV projection (writes q,k,vT planes) ------------
__global__ __launch_bounds__(256) void qkv128_k(const uint16_t* __restrict__ X,
                                                const uint16_t* __restrict__ WT,
                                                const void* __restrict__ bias,
                                                uint16_t* __restrict__ planes,
                                                const int* __restrict__ flag) {
  __shared__ __align__(16) uint16_t As[128 * 32];
  __shared__ __align__(16) uint16_t Bs[128 * 32];
  __shared__ __align__(16) uint16_t Ts[64][136];
  const int fl = *flag;
  const int m0 = blockIdx.x * 128, n0 = blockIdx.y * 128;
  f32x4 acc[4][4];
#pragma unroll
  for (int i = 0; i < 4; ++i)
#pragma unroll
    for (int f = 0; f < 4; ++f) acc[i][f] = (f32x4){0.f, 0.f, 0.f, 0.f};
  gemm128_core(X, WT, m0, n0, As, Bs, acc);

  const int tid = threadIdx.x, lane = tid & 63, w = tid >> 6;
  const int quad = lane >> 4, c16 = lane & 15;
  const int wm = w >> 1, wn = w & 1;
  const int which = (n0 >= 2 * DD) ? 2 : (n0 >= DD ? 1 : 0);

  if (which < 2) {
    uint16_t* dst = planes + (size_t)which * PLANE;
    const float sc = (which == 0) ? SQSCALE : 1.0f;
#pragma unroll
    for (int f = 0; f < 4; ++f) {
      int n = n0 + wn * 64 + f * 16 + c16;
      float bv = fl ? ((const float*)bias)[n] : bf2f(((const uint16_t*)bias)[n]);
      int rem = n - which * DD;
      int hh = rem >> 6, dd = rem & 63;
#pragma unroll
      for (int i = 0; i < 4; ++i)
#pragma unroll
        for (int r = 0; r < 4; ++r) {
          int m = m0 + wm * 64 + i * 16 + quad * 4 + r;
          int b = m >> 12, l = m & (LL - 1);
          dst[((size_t)(b * HH + hh) * LL + l) * DH + dd] = f2bf((acc[i][f][r] + bv) * sc);
        }
    }
  } else {
    uint16_t* vtp = planes + 2 * PLANE;
    const int l0 = m0 & (LL - 1), bb = m0 >> 12;
    for (int half = 0; half < 2; ++half) {
      __syncthreads();
      if (wn == half) {
#pragma unroll
        for (int f = 0; f < 4; ++f) {
          int n = n0 + half * 64 + f * 16 + c16;
          float bv = fl ? ((const float*)bias)[n] : bf2f(((const uint16_t*)bias)[n]);
#pragma unroll
          for (int i = 0; i < 4; ++i)
#pragma unroll
            for (int r = 0; r < 4; ++r)
              Ts[f * 16 + c16][wm * 64 + i * 16 + quad * 4 + r] = f2bf(acc[i][f][r] + bv);
        }
      }
      __syncthreads();
#pragma unroll
      for (int j = 0; j < 4; ++j) {
        int idx = tid + j * 256;
        int nl = idx >> 4, ch = idx & 15;
        int rem = n0 + half * 64 + nl - 2 * DD;
        int hh = rem >> 6, dd = rem & 63;
        uint4 val = *(const uint4*)(&Ts[nl][ch * 8]);
        *(uint4*)(vtp + ((size_t)(bb * HH + hh) * DH + dd) * LL + l0 + ch * 8) = val;
      }
    }
  }
}

// ---------------- kernel: flash attention (causal, paired q-tiles) ---------
// S^T orientation + no-max softmax + packed-b64 P transpose + LDS dbuf.
__global__ __launch_bounds__(256) void attn_k(const uint16_t* __restrict__ planes,
                                              uint16_t* __restrict__ y) {
  __shared__ __align__(16) uint16_t Ks[2][64 * 64];
  __shared__ __align__(16) uint16_t Vt[2][64 * 64];
  __shared__ __align__(16) uint16_t Ps[4][16 * 64];
  const int p = blockIdx.x;            // 0..31 -> q tiles {63-p, p}
  const int bh = blockIdx.y;           // 0..23
  const uint16_t* qb = planes + (size_t)bh * LL * DH;
  const uint16_t* kb = qb + PLANE;
  const uint16_t* vtb = planes + 2 * PLANE + (size_t)bh * DH * LL;  // [d][L]
  const int tid = threadIdx.x, lane = tid & 63, wv = tid >> 6;
  const int quad = lane >> 4, c16 = lane & 15;
  const int r0 = tid >> 3, c0 = tid & 7;
  const int sw0 = r0 & 7;
  const int swf = c16 & 7;
  uint16_t* Psb = Ps[wv];
  const int b = bh / HH, hh = bh - b * HH;
  // P-transpose LDS offsets (uint16 units). Write: 4 consecutive keys (one
  // b64) per f at row q=c16, chunk (f*4+quad)^c16. Read: A-frag chunks.
  const int pwbase = c16 * 64;
  const int prd0 = pwbase + (((2 * quad) ^ c16) << 2);
  const int prd1 = pwbase + (((2 * quad + 1) ^ c16) << 2);
  const int prd2 = pwbase + (((8 + 2 * quad) ^ c16) << 2);
  const int prd3 = pwbase + (((8 + 2 * quad + 1) ^ c16) << 2);

  for (int pass = 0; pass < 2; ++pass) {
    const int qi = pass ? p : 63 - p;
    const int q0 = qi * 64;
    const size_t qoff = (size_t)(q0 + wv * 16 + c16) * DH;
    bf16x8 qf0 = *(const bf16x8*)(qb + qoff + quad * 8);
    bf16x8 qf1 = *(const bf16x8*)(qb + qoff + 32 + quad * 8);

    f32x4 o[4];
#pragma unroll
    for (int g = 0; g < 4; ++g) o[g] = (f32x4){0.f, 0.f, 0.f, 0.f};
    float l_i = 0.f;                   // per-lane partial row-sum for q=c16

    uint4 kr0 = *(const uint4*)(kb + (size_t)r0 * DH + c0 * 8);
    uint4 kr1 = *(const uint4*)(kb + (size_t)(r0 + 32) * DH + c0 * 8);
    uint4 vr0 = *(const uint4*)(vtb + (size_t)r0 * LL + c0 * 8);
    uint4 vr1 = *(const uint4*)(vtb + (size_t)(r0 + 32) * LL + c0 * 8);

    for (int t = 0; t <= qi; ++t) {
      uint16_t* kd = Ks[t & 1];
      uint16_t* vd = Vt[t & 1];
      *(uint4*)(kd + r0 * 64 + (c0 ^ sw0) * 8) = kr0;
      *(uint4*)(kd + (r0 + 32) * 64 + (c0 ^ sw0) * 8) = kr1;
      *(uint4*)(vd + r0 * 64 + (c0 ^ sw0) * 8) = vr0;
      *(uint4*)(vd + (r0 + 32) * 64 + (c0 ^ sw0) * 8) = vr1;
      if (t < qi) {
        int t64 = (t + 1) * 64;
        kr0 = *(const uint4*)(kb + (size_t)(t64 + r0) * DH + c0 * 8);
        kr1 = *(const uint4*)(kb + (size_t)(t64 + r0 + 32) * DH + c0 * 8);
        vr0 = *(const uint4*)(vtb + (size_t)r0 * LL + t64 + c0 * 8);
        vr1 = *(const uint4*)(vtb + (size_t)(r0 + 32) * LL + t64 + c0 * 8);
      }
      __syncthreads();                 // buf (t&1) fully staged by all waves

      // S^T = K Q^T: D[key=quad*4+r (+16f)][q=c16]
      f32x4 s[4];
#pragma unroll
      for (int f = 0; f < 4; ++f) {
        const uint16_t* krow = kd + (f * 16 + c16) * 64;
        bf16x8 k0f = *(const bf16x8*)(krow + ((quad ^ swf) * 8));
        bf16x8 k1f = *(const bf16x8*)(krow + (((quad + 4) ^ swf) * 8));
        f32x4 z = {0.f, 0.f, 0.f, 0.f};
        z = __builtin_amdgcn_mfma_f32_16x16x32_bf16(k0f, qf0, z, 0, 0, 0);
        z = __builtin_amdgcn_mfma_f32_16x16x32_bf16(k1f, qf1, z, 0, 0, 0);
        s[f] = z;
      }
      // no-max softmax: p = exp2(s) (q pre-scaled by 0.125*log2e)
      const int qg = q0 + wv * 16 + c16;
      if (t == qi) {                   // diagonal tile: causal mask
#pragma unroll
        for (int f = 0; f < 4; ++f) {
          int key0 = t * 64 + f * 16 + quad * 4;
#pragma unroll
          for (int r = 0; r < 4; ++r) {
            float pv = exp2f(s[f][r]);
            pv = (key0 + r <= qg) ? pv : 0.f;
            s[f][r] = pv;
            l_i += pv;
          }
        }
      } else {
#pragma unroll
        for (int f = 0; f < 4; ++f)
#pragma unroll
          for (int r = 0; r < 4; ++r) {
            float pv = exp2f(s[f][r]);
            s[f][r] = pv;
            l_i += pv;
          }
      }
      // P transpose: 4 packed b64 writes (4 consecutive keys each)
#pragma unroll
      for (int f = 0; f < 4; ++f) {
        uint32_t w0 = ((uint32_t)f2bf(s[f][1]) << 16) | f2bf(s[f][0]);
        uint32_t w1 = ((uint32_t)f2bf(s[f][3]) << 16) | f2bf(s[f][2]);
        *(uint2*)(Psb + pwbase + (((f * 4 + quad) ^ c16) << 2)) = make_uint2(w0, w1);
      }
      __asm__ __volatile__("s_waitcnt lgkmcnt(0)" ::: "memory");
      B8 p0, p1;
      p0.d[0] = *(const uint2*)(Psb + prd0);
      p0.d[1] = *(const uint2*)(Psb + prd1);
      p1.d[0] = *(const uint2*)(Psb + prd2);
      p1.d[1] = *(const uint2*)(Psb + prd3);
#pragma unroll
      for (int g = 0; g < 4; ++g) {
        const uint16_t* vrow = vd + (g * 16 + c16) * 64;
        bf16x8 v0 = *(const bf16x8*)(vrow + ((quad ^ swf) * 8));
        bf16x8 v1 = *(const bf16x8*)(vrow + (((quad + 4) ^ swf) * 8));
        o[g] = __builtin_amdgcn_mfma_f32_16x16x32_bf16(p0.v, v0, o[g], 0, 0, 0);
        o[g] = __builtin_amdgcn_mfma_f32_16x16x32_bf16(p1.v, v1, o[g], 0, 0, 0);
      }
    }

    // l: reduce across quads (each quad summed its 16 of 64 keys)
    l_i += __shfl_xor(l_i, 16);
    l_i += __shfl_xor(l_i, 32);
    float inv[4];
#pragma unroll
    for (int r = 0; r < 4; ++r)
      inv[r] = 1.f / __shfl(l_i, (quad << 4) + quad * 4 + r);
#pragma unroll
    for (int g = 0; g < 4; ++g)
#pragma unroll
      for (int r = 0; r < 4; ++r) {
        int l = q0 + wv * 16 + quad * 4 + r;
        y[((size_t)(b * LL + l)) * DD + hh * DH + g * 16 + c16] = f2bf(o[g][r] * inv[r]);
      }
    __syncthreads();   // protect K/V buffers before next pass reuses them
  }
}

// ---------------- kernel: output projection --------------------------------
__global__ __launch_bounds__(256) void out128_k(const uint16_t* __restrict__ Y,
                                                const uint16_t* __restrict__ WT,
                                                const void* __restrict__ bias,
                                                void* __restrict__ out,
                                                const int* __restrict__ flag) {
  __shared__ __align__(16) uint16_t As[128 * 32];
  __shared__ __align__(16) uint16_t Bs[128 * 32];
  const int fl = *flag;
  const int m0 = blockIdx.x * 128, n0 = blockIdx.y * 128;
  f32x4 acc[4][4];
#pragma unroll
  for (int i = 0; i < 4; ++i)
#pragma unroll
    for (int f = 0; f < 4; ++f) acc[i][f] = (f32x4){0.f, 0.f, 0.f, 0.f};
  gemm128_core(Y, WT, m0, n0, As, Bs, acc);
  const int lane = threadIdx.x & 63, w = threadIdx.x >> 6;
  const int quad = lane >> 4, c16 = lane & 15;
  const int wm = w >> 1, wn = w & 1;
#pragma unroll
  for (int f = 0; f < 4; ++f) {
    int n = n0 + wn * 64 + f * 16 + c16;
    float bv = fl ? ((const float*)bias)[n] : bf2f(((const uint16_t*)bias)[n]);
#pragma unroll
    for (int i = 0; i < 4; ++i)
#pragma unroll
      for (int r = 0; r < 4; ++r) {
        int m = m0 + wm * 64 + i * 16 + quad * 4 + r;
        float val = acc[i][f][r] + bv;
        if (fl) ((float*)out)[(size_t)m * DD + n] = val;
        else    ((uint16_t*)out)[(size_t)m * DD + n] = f2bf(val);
      }
  }
}

extern "C" void kernel_launch(void* const* d_in, const int* in_sizes, int n_in,
                              void* d_out, int out_size, void* d_ws, size_t ws_size,
                              hipStream_t stream) {
  const void* x    = d_in[0];
  const void* Wqkv = d_in[1];
  const void* bqkv = d_in[2];
  const void* Wo   = d_in[3];
  const void* bo   = d_in[4];
  int* flagp = (int*)d_ws;
  uint16_t* planes = (uint16_t*)((char*)d_ws + 64);
  uint16_t* y_ws   = planes + 3 * PLANE;
  uint16_t* wqkvT  = y_ws + (size_t)MM * DD;
  uint16_t* woT    = wqkvT + (size_t)NQKV * KK;
  uint16_t* xbf    = y_ws;   // overlay: consumed before attn writes y

  detect_k<<<1, 256, 0, stream>>>((const uint16_t*)x, flagp);
  convert_x_k<<<1024, 256, 0, stream>>>(x, xbf, flagp);
  wt_k<<<dim3(NQKV / 64, KK / 64), 256, 0, stream>>>(Wqkv, wqkvT, NQKV, flagp);
  wt_k<<<dim3(DD / 64, KK / 64), 256, 0, stream>>>(Wo, woT, DD, flagp);
  qkv128_k<<<dim3(MM / 128, NQKV / 128), 256, 0, stream>>>(xbf, wqkvT, bqkv, planes, flagp);
  attn_k<<<dim3(32, BB * HH), 256, 0, stream>>>(planes, y_ws);
  out128_k<<<dim3(MM / 128, DD / 128), 256, 0, stream>>>(y_ws, woT, bo, d_out, flagp);
}

// Round 5
// 271.008 us; speedup vs baseline: 2.8148x; 1.0563x over previous
//
#include <hip/hip_runtime.h>
#include <hip/hip_bf16.h>
#include <stdint.h>

// CausalSelfAttention  B=2 L=4096 D=768 H=12 Dh=64
// Dual-dtype inputs (fp32 reference or bf16-lowered), detected on device.
// Internals bf16 MFMA. ws: flag(64B) | q,k planes [bh][l][64] | vT plane
// [bh][d][L] | y/xbf overlay [8192][768] | WqkvT [2304][768] | WoT [768][768]
#define BB 2
#define LL 4096
#define DD 768
#define HH 12
#define DH 64
#define MM (BB * LL)
#define NQKV (3 * DD)
#define KK 768
#define PLANE ((size_t)BB * HH * LL * DH)
#define SQSCALE 0.1803368801111204f   // 0.125 * log2(e)

typedef __attribute__((ext_vector_type(8))) short bf16x8;
typedef __attribute__((ext_vector_type(4))) float f32x4;

__device__ __forceinline__ float bf2f(uint16_t u) {
  union { uint32_t u; float f; } c; c.u = ((uint32_t)u) << 16; return c.f;
}
__device__ __forceinline__ uint16_t f2bf(float f) {
  union { float f; uint32_t u; } c; c.f = f;
  return (uint16_t)((c.u + 0x7FFFu + ((c.u >> 16) & 1u)) >> 16);
}
// packed 2xf32 -> 2xbf16 (v_cvt_pk_bf16_f32); a in low 16, b in high 16
__device__ __forceinline__ uint32_t cvt2(float a, float b) {
  __hip_bfloat162 h = __float22bfloat162_rn(make_float2(a, b));
  union { __hip_bfloat162 h; uint32_t u; } c; c.h = h; return c.u;
}

union H8 { uint16_t h[8]; uint32_t w[4]; uint4 v; };
union B8 { uint2 d[2]; bf16x8 v; };

template <bool F32>
__device__ __forceinline__ H8 load8(const void* p, size_t idx) {
  H8 r;
  if (F32) {
    const float* f = (const float*)p + idx;
    float4 a = *(const float4*)f;
    float4 b = *(const float4*)(f + 4);
    r.w[0] = cvt2(a.x, a.y); r.w[1] = cvt2(a.z, a.w);
    r.w[2] = cvt2(b.x, b.y); r.w[3] = cvt2(b.z, b.w);
  } else {
    r.v = *(const uint4*)((const uint16_t*)p + idx);
  }
  return r;
}

// async global->LDS, 16B per lane; lds ptr must be wave-uniform
__device__ __forceinline__ void g2l16(const uint16_t* g, uint16_t* l) {
  __builtin_amdgcn_global_load_lds((const __attribute__((address_space(1))) void*)g,
                                   (__attribute__((address_space(3))) void*)l,
                                   16, 0, 0);
}

// ---------------- dtype detection ------------------------------------------
__global__ void detect_k(const uint16_t* __restrict__ x, int* __restrict__ flag) {
  __shared__ int cnt;
  if (threadIdx.x == 0) cnt = 0;
  __syncthreads();
  int c = 0;
  for (int i = threadIdx.x; i < 4096; i += 256) {
    int e = (x[i] >> 7) & 0xFF;
    if (e == 0xFF || e > 133 || e < 100) c++;
  }
  atomicAdd(&cnt, c);
  __syncthreads();
  if (threadIdx.x == 0) *flag = (cnt > 512) ? 1 : 0;
}

// ---------------- merged prep: x->bf16, WqkvT, WoT -------------------------
// grid.x = 768 (convert) + 432 (WqkvT) + 144 (WoT)
__global__ __launch_bounds__(256) void prep_k(const void* __restrict__ x,
                                              uint16_t* __restrict__ xbf,
                                              const void* __restrict__ Wqkv,
                                              uint16_t* __restrict__ wqkvT,
                                              const void* __restrict__ Wo,
                                              uint16_t* __restrict__ woT,
                                              const int* __restrict__ flag) {
  __shared__ uint16_t Ts[64][65];
  const int fl = *flag;
  const int id = blockIdx.x;
  const int tid = threadIdx.x;
  if (id < 768) {
    // x convert: 786432 chunks of 8, 1024 per block
    size_t base = (size_t)id * 1024 + tid;
#pragma unroll
    for (int j = 0; j < 4; ++j) {
      size_t i = base + j * 256;
      H8 v = fl ? load8<true>(x, i * 8) : load8<false>(x, i * 8);
      *(uint4*)(xbf + i * 8) = v.v;
    }
    return;
  }
  const void* W;
  uint16_t* WT;
  int N, widx;
  if (id < 1200) { W = Wqkv; WT = wqkvT; N = NQKV; widx = id - 768; }
  else           { W = Wo;   WT = woT;   N = DD;   widx = id - 1200; }
  const int nb = N / 64;
  const int n0 = (widx % nb) * 64, k0 = (widx / nb) * 64;
#pragma unroll
  for (int j = 0; j < 16; ++j) {
    int idx = tid + j * 256;
    int r = idx >> 6, c = idx & 63;
    size_t gi = (size_t)(k0 + r) * N + n0 + c;
    float v = fl ? ((const float*)W)[gi] : bf2f(((const uint16_t*)W)[gi]);
    Ts[c][r] = f2bf(v);
  }
  __syncthreads();
#pragma unroll
  for (int j = 0; j < 16; ++j) {
    int idx = tid + j * 256;
    int n = idx >> 6, k = idx & 63;
    WT[(size_t)(n0 + n) * KK + k0 + k] = Ts[n][k];
  }
}

// ---------------- 128x128 GEMM core (K=768, BK=32, global_load_lds) --------
__device__ __forceinline__ void gemm128_core(const uint16_t* __restrict__ A,
                                             const uint16_t* __restrict__ BT,
                                             int m0, int n0,
                                             uint16_t* As, uint16_t* Bs,
                                             f32x4 acc[4][4]) {
  const int tid = threadIdx.x, lane = tid & 63, w = tid >> 6;
  const int quad = lane >> 4, c16 = lane & 15;
  const int wm = w >> 1, wn = w & 1;
  const int srow = lane >> 2, schunk = lane & 3;
  const int rsw = (c16 >> 1) & 3;
  for (int k0 = 0; k0 < KK; k0 += 32) {
#pragma unroll
    for (int i = 0; i < 2; ++i) {
      int row = w * 32 + i * 16 + srow;
      int gch = schunk ^ ((row >> 1) & 3);
      g2l16(A + (size_t)(m0 + row) * KK + k0 + gch * 8, As + (w * 32 + i * 16) * 32);
      g2l16(BT + (size_t)(n0 + row) * KK + k0 + gch * 8, Bs + (w * 32 + i * 16) * 32);
    }
    __syncthreads();
    bf16x8 a[4], b[4];
#pragma unroll
    for (int i = 0; i < 4; ++i) {
      a[i] = *(const bf16x8*)(As + (wm * 64 + i * 16 + c16) * 32 + ((quad ^ rsw) * 8));
      b[i] = *(const bf16x8*)(Bs + (wn * 64 + i * 16 + c16) * 32 + ((quad ^ rsw) * 8));
    }
#pragma unroll
    for (int i = 0; i < 4; ++i)
#pragma unroll
      for (int f = 0; f < 4; ++f)
        acc[i][f] = __builtin_amdgcn_mfma_f32_16x16x32_bf16(a[i], b[f], acc[i][f], 0, 0, 0);
    __syncthreads();
  }
}

// ---------------- kernel: QKV projection (writes q,k,vT planes) ------------
__global__ __launch_bounds__(256) void qkv128_k(const uint16_t* __restrict__ X,
                                                const uint16_t* __restrict__ WT,
                                                const void* __restrict__ bias,
                                                uint16_t* __restrict__ planes,
                                                const int* __restrict__ flag) {
  __shared__ __align__(16) uint16_t As[128 * 32];
  __shared__ __align__(16) uint16_t Bs[128 * 32];
  __shared__ __align__(16) uint16_t Ts[64][136];
  const int fl = *flag;
  const int m0 = blockIdx.x * 128, n0 = blockIdx.y * 128;
  f32x4 acc[4][4];
#pragma unroll
  for (int i = 0; i < 4; ++i)
#pragma unroll
    for (int f = 0; f < 4; ++f) acc[i][f] = (f32x4){0.f, 0.f, 0.f, 0.f};
  gemm128_core(X, WT, m0, n0, As, Bs, acc);

  const int tid = threadIdx.x, lane = tid & 63, w = tid >> 6;
  const int quad = lane >> 4, c16 = lane & 15;
  const int wm = w >> 1, wn = w & 1;
  const int which = (n0 >= 2 * DD) ? 2 : (n0 >= DD ? 1 : 0);

  if (which < 2) {
    uint16_t* dst = planes + (size_t)which * PLANE;
    const float sc = (which == 0) ? SQSCALE : 1.0f;
#pragma unroll
    for (int f = 0; f < 4; ++f) {
      int n = n0 + wn * 64 + f * 16 + c16;
      float bv = fl ? ((const float*)bias)[n] : bf2f(((const uint16_t*)bias)[n]);
      int rem = n - which * DD;
      int hh = rem >> 6, dd = rem & 63;
#pragma unroll
      for (int i = 0; i < 4; ++i) {
        uint32_t pa = cvt2((acc[i][f][0] + bv) * sc, (acc[i][f][1] + bv) * sc);
        uint32_t pb = cvt2((acc[i][f][2] + bv) * sc, (acc[i][f][3] + bv) * sc);
        int m = m0 + wm * 64 + i * 16 + quad * 4;
        int b = m >> 12, l = m & (LL - 1);
        uint16_t* base = dst + ((size_t)(b * HH + hh) * LL + l) * DH + dd;
        base[0 * DH] = (uint16_t)pa;
        base[1 * DH] = (uint16_t)(pa >> 16);
        base[2 * DH] = (uint16_t)pb;
        base[3 * DH] = (uint16_t)(pb >> 16);
      }
    }
  } else {
    uint16_t* vtp = planes + 2 * PLANE;
    const int l0 = m0 & (LL - 1), bb = m0 >> 12;
    for (int half = 0; half < 2; ++half) {
      __syncthreads();
      if (wn == half) {
#pragma unroll
        for (int f = 0; f < 4; ++f) {
          int n = n0 + half * 64 + f * 16 + c16;
          float bv = fl ? ((const float*)bias)[n] : bf2f(((const uint16_t*)bias)[n]);
#pragma unroll
          for (int i = 0; i < 4; ++i) {
            uint32_t pa = cvt2(acc[i][f][0] + bv, acc[i][f][1] + bv);
            uint32_t pb = cvt2(acc[i][f][2] + bv, acc[i][f][3] + bv);
            *(uint2*)(&Ts[f * 16 + c16][wm * 64 + i * 16 + quad * 4]) = make_uint2(pa, pb);
          }
        }
      }
      __syncthreads();
#pragma unroll
      for (int j = 0; j < 4; ++j) {
        int idx = tid + j * 256;
        int nl = idx >> 4, ch = idx & 15;
        int rem = n0 + half * 64 + nl - 2 * DD;
        int hh = rem >> 6, dd = rem & 63;
        uint4 val = *(const uint4*)(&Ts[nl][ch * 8]);
        *(uint4*)(vtp + ((size_t)(bb * HH + hh) * DH + dd) * LL + l0 + ch * 8) = val;
      }
    }
  }
}

// ---------------- kernel: flash attention (causal, paired q-tiles) ---------
// S^T orientation + no-max softmax + packed P transpose + LDS dbuf.
__global__ __launch_bounds__(256) void attn_k(const uint16_t* __restrict__ planes,
                                              uint16_t* __restrict__ y) {
  __shared__ __align__(16) uint16_t Ks[2][64 * 64];
  __shared__ __align__(16) uint16_t Vt[2][64 * 64];
  __shared__ __align__(16) uint16_t Ps[4][16 * 64];
  const int p = blockIdx.x;            // 0..31 -> q tiles {63-p, p}
  const int bh = blockIdx.y;           // 0..23
  const uint16_t* qb = planes + (size_t)bh * LL * DH;
  const uint16_t* kb = qb + PLANE;
  const uint16_t* vtb = planes + 2 * PLANE + (size_t)bh * DH * LL;  // [d][L]
  const int tid = threadIdx.x, lane = tid & 63, wv = tid >> 6;
  const int quad = lane >> 4, c16 = lane & 15;
  const int r0 = tid >> 3, c0 = tid & 7;
  const int sw0 = r0 & 7;
  const int swf = c16 & 7;
  uint16_t* Psb = Ps[wv];
  const int b = bh / HH, hh = bh - b * HH;
  const int pwbase = c16 * 64;
  const int prd0 = pwbase + (((2 * quad) ^ c16) << 2);
  const int prd1 = pwbase + (((2 * quad + 1) ^ c16) << 2);
  const int prd2 = pwbase + (((8 + 2 * quad) ^ c16) << 2);
  const int prd3 = pwbase + (((8 + 2 * quad + 1) ^ c16) << 2);

  for (int pass = 0; pass < 2; ++pass) {
    const int qi = pass ? p : 63 - p;
    const int q0 = qi * 64;
    const size_t qoff = (size_t)(q0 + wv * 16 + c16) * DH;
    bf16x8 qf0 = *(const bf16x8*)(qb + qoff + quad * 8);
    bf16x8 qf1 = *(const bf16x8*)(qb + qoff + 32 + quad * 8);

    f32x4 o[4];
#pragma unroll
    for (int g = 0; g < 4; ++g) o[g] = (f32x4){0.f, 0.f, 0.f, 0.f};
    float l_i = 0.f;

    uint4 kr0 = *(const uint4*)(kb + (size_t)r0 * DH + c0 * 8);
    uint4 kr1 = *(const uint4*)(kb + (size_t)(r0 + 32) * DH + c0 * 8);
    uint4 vr0 = *(const uint4*)(vtb + (size_t)r0 * LL + c0 * 8);
    uint4 vr1 = *(const uint4*)(vtb + (size_t)(r0 + 32) * LL + c0 * 8);

    for (int t = 0; t <= qi; ++t) {
      uint16_t* kd = Ks[t & 1];
      uint16_t* vd = Vt[t & 1];
      *(uint4*)(kd + r0 * 64 + (c0 ^ sw0) * 8) = kr0;
      *(uint4*)(kd + (r0 + 32) * 64 + (c0 ^ sw0) * 8) = kr1;
      *(uint4*)(vd + r0 * 64 + (c0 ^ sw0) * 8) = vr0;
      *(uint4*)(vd + (r0 + 32) * 64 + (c0 ^ sw0) * 8) = vr1;
      if (t < qi) {
        int t64 = (t + 1) * 64;
        kr0 = *(const uint4*)(kb + (size_t)(t64 + r0) * DH + c0 * 8);
        kr1 = *(const uint4*)(kb + (size_t)(t64 + r0 + 32) * DH + c0 * 8);
        vr0 = *(const uint4*)(vtb + (size_t)r0 * LL + t64 + c0 * 8);
        vr1 = *(const uint4*)(vtb + (size_t)(r0 + 32) * LL + t64 + c0 * 8);
      }
      __syncthreads();

      // S^T = K Q^T: D[key=quad*4+r (+16f)][q=c16]
      f32x4 s[4];
#pragma unroll
      for (int f = 0; f < 4; ++f) {
        const uint16_t* krow = kd + (f * 16 + c16) * 64;
        bf16x8 k0f = *(const bf16x8*)(krow + ((quad ^ swf) * 8));
        bf16x8 k1f = *(const bf16x8*)(krow + (((quad + 4) ^ swf) * 8));
        f32x4 z = {0.f, 0.f, 0.f, 0.f};
        z = __builtin_amdgcn_mfma_f32_16x16x32_bf16(k0f, qf0, z, 0, 0, 0);
        z = __builtin_amdgcn_mfma_f32_16x16x32_bf16(k1f, qf1, z, 0, 0, 0);
        s[f] = z;
      }
      const int qg = q0 + wv * 16 + c16;
      if (t == qi) {
#pragma unroll
        for (int f = 0; f < 4; ++f) {
          int key0 = t * 64 + f * 16 + quad * 4;
#pragma unroll
          for (int r = 0; r < 4; ++r) {
            float pv = exp2f(s[f][r]);
            pv = (key0 + r <= qg) ? pv : 0.f;
            s[f][r] = pv;
            l_i += pv;
          }
        }
      } else {
#pragma unroll
        for (int f = 0; f < 4; ++f)
#pragma unroll
          for (int r = 0; r < 4; ++r) {
            float pv = exp2f(s[f][r]);
            s[f][r] = pv;
            l_i += pv;
          }
      }
#pragma unroll
      for (int f = 0; f < 4; ++f) {
        uint32_t w0 = cvt2(s[f][0], s[f][1]);
        uint32_t w1 = cvt2(s[f][2], s[f][3]);
        *(uint2*)(Psb + pwbase + (((f * 4 + quad) ^ c16) << 2)) = make_uint2(w0, w1);
      }
      __asm__ __volatile__("s_waitcnt lgkmcnt(0)" ::: "memory");
      B8 p0, p1;
      p0.d[0] = *(const uint2*)(Psb + prd0);
      p0.d[1] = *(const uint2*)(Psb + prd1);
      p1.d[0] = *(const uint2*)(Psb + prd2);
      p1.d[1] = *(const uint2*)(Psb + prd3);
#pragma unroll
      for (int g = 0; g < 4; ++g) {
        const uint16_t* vrow = vd + (g * 16 + c16) * 64;
        bf16x8 v0 = *(const bf16x8*)(vrow + ((quad ^ swf) * 8));
        bf16x8 v1 = *(const bf16x8*)(vrow + (((quad + 4) ^ swf) * 8));
        o[g] = __builtin_amdgcn_mfma_f32_16x16x32_bf16(p0.v, v0, o[g], 0, 0, 0);
        o[g] = __builtin_amdgcn_mfma_f32_16x16x32_bf16(p1.v, v1, o[g], 0, 0, 0);
      }
    }

    l_i += __shfl_xor(l_i, 16);
    l_i += __shfl_xor(l_i, 32);
    float inv[4];
#pragma unroll
    for (int r = 0; r < 4; ++r)
      inv[r] = 1.f / __shfl(l_i, (quad << 4) + quad * 4 + r);
#pragma unroll
    for (int g = 0; g < 4; ++g) {
      uint32_t pa = cvt2(o[g][0] * inv[0], o[g][1] * inv[1]);
      uint32_t pb = cvt2(o[g][2] * inv[2], o[g][3] * inv[3]);
      int l = q0 + wv * 16 + quad * 4;
      uint16_t* base = y + ((size_t)(b * LL + l)) * DD + hh * DH + g * 16 + c16;
      base[0 * DD] = (uint16_t)pa;
      base[1 * DD] = (uint16_t)(pa >> 16);
      base[2 * DD] = (uint16_t)pb;
      base[3 * DD] = (uint16_t)(pb >> 16);
    }
    __syncthreads();   // protect K/V buffers before next pass
  }
}

// ---------------- kernel: output projection --------------------------------
__global__ __launch_bounds__(256) void out128_k(const uint16_t* __restrict__ Y,
                                                const uint16_t* __restrict__ WT,
                                                const void* __restrict__ bias,
                                                void* __restrict__ out,
                                                const int* __restrict__ flag) {
  __shared__ __align__(16) uint16_t As[128 * 32];
  __shared__ __align__(16) uint16_t Bs[128 * 32];
  const int fl = *flag;
  const int m0 = blockIdx.x * 128, n0 = blockIdx.y * 128;
  f32x4 acc[4][4];
#pragma unroll
  for (int i = 0; i < 4; ++i)
#pragma unroll
    for (int f = 0; f < 4; ++f) acc[i][f] = (f32x4){0.f, 0.f, 0.f, 0.f};
  gemm128_core(Y, WT, m0, n0, As, Bs, acc);
  const int lane = threadIdx.x & 63, w = threadIdx.x >> 6;
  const int quad = lane >> 4, c16 = lane & 15;
  const int wm = w >> 1, wn = w & 1;
#pragma unroll
  for (int f = 0; f < 4; ++f) {
    int n = n0 + wn * 64 + f * 16 + c16;
    float bv = fl ? ((const float*)bias)[n] : bf2f(((const uint16_t*)bias)[n]);
#pragma unroll
    for (int i = 0; i < 4; ++i) {
      int m = m0 + wm * 64 + i * 16 + quad * 4;
      if (fl) {
        float* base = (float*)out + (size_t)m * DD + n;
#pragma unroll
        for (int r = 0; r < 4; ++r) base[r * DD] = acc[i][f][r] + bv;
      } else {
        uint32_t pa = cvt2(acc[i][f][0] + bv, acc[i][f][1] + bv);
        uint32_t pb = cvt2(acc[i][f][2] + bv, acc[i][f][3] + bv);
        uint16_t* base = (uint16_t*)out + (size_t)m * DD + n;
        base[0 * DD] = (uint16_t)pa;
        base[1 * DD] = (uint16_t)(pa >> 16);
        base[2 * DD] = (uint16_t)pb;
        base[3 * DD] = (uint16_t)(pb >> 16);
      }
    }
  }
}

extern "C" void kernel_launch(void* const* d_in, const int* in_sizes, int n_in,
                              void* d_out, int out_size, void* d_ws, size_t ws_size,
                              hipStream_t stream) {
  const void* x    = d_in[0];
  const void* Wqkv = d_in[1];
  const void* bqkv = d_in[2];
  const void* Wo   = d_in[3];
  const void* bo   = d_in[4];
  int* flagp = (int*)d_ws;
  uint16_t* planes = (uint16_t*)((char*)d_ws + 64);
  uint16_t* y_ws   = planes + 3 * PLANE;
  uint16_t* wqkvT  = y_ws + (size_t)MM * DD;
  uint16_t* woT    = wqkvT + (size_t)NQKV * KK;
  uint16_t* xbf    = y_ws;   // overlay: consumed before attn writes y

  detect_k<<<1, 256, 0, stream>>>((const uint16_t*)x, flagp);
  prep_k<<<1344, 256, 0, stream>>>(x, xbf, Wqkv, wqkvT, Wo, woT, flagp);
  qkv128_k<<<dim3(MM / 128, NQKV / 128), 256, 0, stream>>>(xbf, wqkvT, bqkv, planes, flagp);
  attn_k<<<dim3(32, BB * HH), 256, 0, stream>>>(planes, y_ws);
  out128_k<<<dim3(MM / 128, DD / 128), 256, 0, stream>>>(y_ws, woT, bo, d_out, flagp);
}